// Round 11
// baseline (119.625 us; speedup 1.0000x reference)
//
#include <hip/hip_runtime.h>

#define BB 4096   // batch
#define TT 512    // time steps
#define DD 32     // input dim
#define NL 10     // layers
#define PH 8      // steps per phase
#define PHASES 66 // 528 steps
#define CPB 2     // chains per block (2 -> 2048 blocks -> 2 waves/SIMD)

static constexpr float L2E = 1.4426950408889634f;   // log2(e)

typedef float f4 __attribute__((ext_vector_type(4)));

__device__ __forceinline__ float fexp2(float x) { return __builtin_amdgcn_exp2f(x); }
__device__ __forceinline__ float frcp(float x)  { return __builtin_amdgcn_rcpf(x); }
__device__ __forceinline__ float fmed3(float x, float a, float b) {
    return __builtin_amdgcn_fmed3f(x, a, b);
}

// row_shr:1 within each 16-lane row; row-lane 0 gets 0 (bound_ctrl).
__device__ __forceinline__ float dpp_shr1(float x) {
    int r = __builtin_amdgcn_update_dpp(0, __float_as_int(x), 0x111, 0xF, 0xF, true);
    return __int_as_float(r);
}

// x + dpp_perm(x): pure-VALU lane reduction (no LDS, no lgkmcnt).
template<int CTRL>
__device__ __forceinline__ float dpp_add(float x) {
    return x + __int_as_float(__builtin_amdgcn_update_dpp(
        0, __float_as_int(x), CTRL, 0xF, 0xF, true));
}
#define DPP_XOR1 0xB1   // quad_perm [1,0,3,2]
#define DPP_XOR2 0x4E   // quad_perm [2,3,0,1]
#define DPP_ROR4 0x124  // row_ror:4 cross-quad gather (verified by R10 pass)

// ---------------------------------------------------------------------------
// R11: same fused structure as R10, but CPB=2 chains/wave and 2048 blocks
// -> 2 waves/SIMD so the two waves hide each other's stalls (latency chain,
// DPP hazards, residual waits). Rows 2,3 of each wave idle (consumer side
// masked); producer role unchanged (all 64 lanes, now 2 chains).
// ---------------------------------------------------------------------------
__global__ __launch_bounds__(64) void k_fused(
    const float* __restrict__ x, const float* __restrict__ Wih0,
    const float* __restrict__ Whh0, const float* __restrict__ b0,
    const float* __restrict__ Wihr, const float* __restrict__ Whhr,
    const float* __restrict__ br, float* __restrict__ out)
{
    __shared__ float4 gbuf[2][CPB][PH + 1];   // [slot][chain][step], +1 pad

    const int lane = threadIdx.x & 63;
    const int blk  = blockIdx.x;

    // ---- producer-role constants ----
    const int pg = lane >> 3;               // step-in-phase this lane helps produce
    const int pc = lane & 7;                // float4 chunk of the 32-wide x row
    const f4 pw0 = *(const f4*)(Wih0 + 0 * DD + pc * 4);
    const f4 pw1 = *(const f4*)(Wih0 + 1 * DD + pc * 4);
    const f4 pw2 = *(const f4*)(Wih0 + 2 * DD + pc * 4);
    const f4 pw3 = *(const f4*)(Wih0 + 3 * DD + pc * 4);
    const float pb0 = b0[0], pb1 = b0[1], pb2 = b0[2], pb3 = b0[3];

    // ---- consumer-role constants ----
    const int cidx = lane >> 4;             // row 0..3; rows >= CPB idle
    const int l = lane & 15;                // 0..9 live layers
    const bool vrow = (cidx < CPB);
    const int cc = vrow ? cidx : 0;         // clamped LDS index for idle rows
    const int chain = blk * CPB + cc;
    const float sk0 = -L2E, sk1 = -L2E, sk2 = -2.f * L2E, sk3 = -L2E;
    const bool isl0 = (l == 0), isl9 = (l == NL - 1);
    const int li = (l >= 1 && l <= 9) ? (l - 1) : 0;

    float wi0 = 0, wi1 = 0, wi2 = 0, wi3 = 0;
    float wh0, wh1, wh2, wh3;
    float bb0 = 0, bb1 = 0, bb2 = 0, bb3 = 0;
    if (isl0) {
        wh0 = sk0 * Whh0[0]; wh1 = sk1 * Whh0[1];
        wh2 = sk2 * Whh0[2]; wh3 = sk3 * Whh0[3];
    } else {
        const float* pi = Wihr + li * 4;
        const float* ph = Whhr + li * 4;
        const float* pb = br   + li * 4;
        wi0 = sk0 * pi[0]; wi1 = sk1 * pi[1]; wi2 = sk2 * pi[2]; wi3 = sk3 * pi[3];
        wh0 = sk0 * ph[0]; wh1 = sk1 * ph[1]; wh2 = sk2 * ph[2]; wh3 = sk3 * ph[3];
        bb0 = sk0 * pb[0]; bb1 = sk1 * pb[1]; bb2 = sk2 * pb[2]; bb3 = sk3 * pb[3];
    }

    float* outp = out + (size_t)chain * TT;
    const float c2 = 2.f * L2E;
    float h = 0.f, cs = 0.f;                // cs = -2*L2E*c
    float o0 = 0.f, o1 = 0.f, o2 = 0.f, o3 = 0.f;

    const float* xb = x + (size_t)blk * CPB * TT * DD;

    f4 VA0, VA1, VB0, VB1;

    auto LOADV = [&](f4& v0, f4& v1, int p) {
        int t = p * PH + pg; t = t < TT ? t : TT - 1;   // tail clamps (discarded)
        const float* base = xb + (size_t)t * DD + pc * 4;
        v0 = __builtin_nontemporal_load((const f4*)(base + 0 * TT * DD));
        v1 = __builtin_nontemporal_load((const f4*)(base + 1 * TT * DD));
    };

    auto PROD1 = [&](const f4 v, int ci, int slot) {    // ci, slot literal at call site
        float p0 = v.x * pw0.x + v.y * pw0.y + v.z * pw0.z + v.w * pw0.w;
        float p1 = v.x * pw1.x + v.y * pw1.y + v.z * pw1.z + v.w * pw1.w;
        float p2 = v.x * pw2.x + v.y * pw2.y + v.z * pw2.z + v.w * pw2.w;
        float p3 = v.x * pw3.x + v.y * pw3.y + v.z * pw3.z + v.w * pw3.w;
        p0 = dpp_add<DPP_XOR1>(p0); p1 = dpp_add<DPP_XOR1>(p1);
        p2 = dpp_add<DPP_XOR1>(p2); p3 = dpp_add<DPP_XOR1>(p3);
        p0 = dpp_add<DPP_XOR2>(p0); p1 = dpp_add<DPP_XOR2>(p1);
        p2 = dpp_add<DPP_XOR2>(p2); p3 = dpp_add<DPP_XOR2>(p3);
        p0 = dpp_add<DPP_ROR4>(p0); p1 = dpp_add<DPP_ROR4>(p1);
        p2 = dpp_add<DPP_ROR4>(p2); p3 = dpp_add<DPP_ROR4>(p3);
        if (pc == 0) {
            float4 o;
            o.x = -L2E * (p0 + pb0);
            o.y = -L2E * (p1 + pb1);
            o.z = -2.f * L2E * (p2 + pb2);
            o.w = -L2E * (p3 + pb3);
            gbuf[slot][ci][pg] = o;
        }
    };

    auto READR = [&](float4* R, int slot) {
        if (isl0) {
#pragma unroll
            for (int j = 0; j < PH; j++) R[j] = gbuf[slot][cc][j];
        }
    };

    auto STEP = [&](float4 g, int s, int jm) {
        int t = s - l;
        bool active = (t >= 0) && (t < TT);

        float hin = dpp_shr1(h);                      // h_{l-1}(t)
        float u0 = fmaf(h, wh0, fmaf(hin, wi0, g.x));
        float u1 = fmaf(h, wh1, fmaf(hin, wi1, g.y));
        float u2 = fmaf(h, wh2, fmaf(hin, wi2, g.z));
        float u3 = fmaf(h, wh3, fmaf(hin, wi3, g.w));

        float E0 = fexp2(u0), E1 = fexp2(u1), E2 = fexp2(u2), E3 = fexp2(u3);
        float A0 = 1.f + E0, A1 = 1.f + E1, A2 = 1.f + E2, A3 = 1.f + E3;
        float q02  = frcp(A0 * A2);
        float num2 = fmaf(E2, c2, -c2);
        float term = num2 * q02;
        float r1   = frcp(A1);
        float csn  = fmaf(cs, r1, term);              // -2L2E*c_new
        csn = fmed3(csn, -88.f, 88.f);                // single-op clamp
        float Ec  = fexp2(csn);
        float Ac  = 1.f + Ec;
        float qc3 = frcp(Ac * A3);
        float hn  = (1.f - Ec) * qc3;

        if (active) { cs = csn; h = hn; }

        if (jm == 1) o0 = hn;
        else if (jm == 2) o1 = hn;
        else if (jm == 3) o2 = hn;
        else o3 = hn;                                  // jm == 0
        if (jm == 0 && s >= 12 && s <= 520 && isl9 && vrow) {
            float4 v;
            v.x = 60.f * frcp(1.f + fexp2(-L2E * o0));
            v.y = 60.f * frcp(1.f + fexp2(-L2E * o1));
            v.z = 60.f * frcp(1.f + fexp2(-L2E * o2));
            v.w = 60.f * frcp(1.f + fexp2(-L2E * o3));
            *(float4*)(outp + (s - 12)) = v;
        }
    };

    float4 RA[PH], RB[PH];
    float4 bbv = make_float4(bb0, bb1, bb2, bb3);
#pragma unroll
    for (int i = 0; i < PH; i++) { RA[i] = bbv; RB[i] = bbv; }

    // prologue: VA<-ph0, VB<-ph1; produce ph0; regs<-ph0; VA<-ph2
    LOADV(VA0, VA1, 0);
    LOADV(VB0, VB1, 1);
    PROD1(VA0, 0, 0); PROD1(VA1, 1, 0);
    READR(RA, 0);
    LOADV(VA0, VA1, 2);

    // steady state: at top RA=regs(ph p), VB=x(ph p+1), VA=x(ph p+2)
    for (int p = 0; p < PHASES; p += 2) {
        PROD1(VB0, 0, 1); PROD1(VB1, 1, 1);
#pragma unroll
        for (int j = 0; j < PH; j++) STEP(RA[j], p * PH + j, j & 3);
        READR(RB, 1);                                  // regs <- ph p+1
        LOADV(VB0, VB1, p + 3);

        PROD1(VA0, 0, 0); PROD1(VA1, 1, 0);
#pragma unroll
        for (int j = 0; j < PH; j++) STEP(RB[j], (p + 1) * PH + j, j & 3);
        READR(RA, 0);                                  // regs <- ph p+2
        LOADV(VA0, VA1, p + 4);
    }
}

extern "C" void kernel_launch(void* const* d_in, const int* in_sizes, int n_in,
                              void* d_out, int out_size, void* d_ws, size_t ws_size,
                              hipStream_t stream)
{
    const float* x    = (const float*)d_in[0];
    const float* Wih0 = (const float*)d_in[1];
    const float* Whh0 = (const float*)d_in[2];
    const float* b0   = (const float*)d_in[3];
    const float* Wihr = (const float*)d_in[4];
    const float* Whhr = (const float*)d_in[5];
    const float* br   = (const float*)d_in[6];
    float* out = (float*)d_out;

    k_fused<<<BB / CPB, 64, 0, stream>>>(x, Wih0, Whh0, b0, Wihr, Whhr, br, out);
}